// Round 4
// baseline (423.942 us; speedup 1.0000x reference)
//
#include <hip/hip_runtime.h>

typedef float        f32x4  __attribute__((ext_vector_type(4)));
typedef __bf16       bf16x8 __attribute__((ext_vector_type(8)));
typedef unsigned int u32x4  __attribute__((ext_vector_type(4)));

#define NN   8192
#define IND  256
#define OUTD 128
#define NB   144    // part cols: 0..127 = num, 128 = den, 129..143 never read
#define KSPLIT 16
#define KRANGE 512  // 8192 / KSPLIT
#define BT_BYTES (144 * 1024)   // 144 rows x 512 k x 2B = 144 KB LDS tile

__device__ __forceinline__ bf16x8 cvt2(f32x4 a, f32x4 b) {
  bf16x8 r;
  r[0]=(__bf16)a[0]; r[1]=(__bf16)a[1]; r[2]=(__bf16)a[2]; r[3]=(__bf16)a[3];
  r[4]=(__bf16)b[0]; r[5]=(__bf16)b[1]; r[6]=(__bf16)b[2]; r[7]=(__bf16)b[3];
  return r;
}

// K1 (fused): Wh = X@W^T via MFMA (4-way K-split across waves, LDS merge),
// e = relu(Wh).a_w (16-lane butterfly allreduce), then write B^T directly:
// Bt[n][j] = exp(e_j)*Wh[j][n] (n<128), Bt[128][j] = exp(e_j), rows 129..143 = 0.
// Wh/ev never touch HBM.
__global__ __launch_bounds__(256) void k1_bt(const float* __restrict__ X,
                                             const float* __restrict__ W,
                                             const float* __restrict__ aw,
                                             __bf16* __restrict__ Bt) {
  __shared__ float red[4][16][128];   // 32 KB
  const int tid  = threadIdx.x;
  const int lane = tid & 63;
  const int wave = tid >> 6;
  const int nlo  = lane & 15;
  const int quad = lane >> 4;
  const int rowBase = blockIdx.x * 16;

  const float* xp = X + (size_t)(rowBase + nlo) * IND + wave * 64 + quad * 8;
  f32x4 acc[8];
#pragma unroll
  for (int nt = 0; nt < 8; ++nt) acc[nt] = f32x4{0.f, 0.f, 0.f, 0.f};

#pragma unroll
  for (int kb = 0; kb < 64; kb += 32) {
    f32x4 a0 = *(const f32x4*)(xp + kb);
    f32x4 a1 = *(const f32x4*)(xp + kb + 4);
    bf16x8 af = cvt2(a0, a1);
#pragma unroll
    for (int nt = 0; nt < 8; ++nt) {
      const float* wp = W + (size_t)(nt * 16 + nlo) * IND + wave * 64 + kb + quad * 8;
      f32x4 b0 = *(const f32x4*)wp;
      f32x4 b1 = *(const f32x4*)(wp + 4);
      acc[nt] = __builtin_amdgcn_mfma_f32_16x16x32_bf16(af, cvt2(b0, b1), acc[nt], 0, 0, 0);
    }
  }
#pragma unroll
  for (int nt = 0; nt < 8; ++nt)
#pragma unroll
    for (int rg = 0; rg < 4; ++rg)
      red[wave][quad * 4 + rg][nt * 16 + nlo] = acc[nt][rg];
  __syncthreads();

  // merge partials: thread t owns row r = t>>4 (j = rowBase+r), cols c0..c0+7
  const int r  = tid >> 4;
  const int c0 = (tid & 15) * 8;
  f32x4 vlo = *(const f32x4*)&red[0][r][c0];
  f32x4 vhi = *(const f32x4*)&red[0][r][c0 + 4];
#pragma unroll
  for (int w = 1; w < 4; ++w) {
    vlo += *(const f32x4*)&red[w][r][c0];
    vhi += *(const f32x4*)&red[w][r][c0 + 4];
  }
  float pa = 0.f;
#pragma unroll
  for (int i = 0; i < 4; ++i) {
    pa += fmaxf(vlo[i], 0.f) * aw[c0 + i];
    pa += fmaxf(vhi[i], 0.f) * aw[c0 + 4 + i];
  }
#pragma unroll
  for (int off = 8; off; off >>= 1) pa += __shfl_xor(pa, off, 64);  // 16-lane allreduce
  const float wexp = expf(pa);
  const int j = rowBase + r;

#pragma unroll
  for (int i = 0; i < 4; ++i)
    Bt[(size_t)(c0 + i) * NN + j] = (__bf16)(vlo[i] * wexp);
#pragma unroll
  for (int i = 0; i < 4; ++i)
    Bt[(size_t)(c0 + 4 + i) * NN + j] = (__bf16)(vhi[i] * wexp);
  if ((tid & 15) == 0)
    Bt[(size_t)OUTD * NN + j] = (__bf16)wexp;           // denominator row
  if (tid < 120) {                                       // zero rows 129..143
    const int row = 129 + (tid >> 3);
    const int cc  = rowBase + (tid & 7) * 2;
    Bt[(size_t)row * NN + cc]     = (__bf16)0.f;
    Bt[(size_t)row * NN + cc + 1] = (__bf16)0.f;
  }
}

// K3a: part[slice][8192 x NB] = Adj(->bf16) @ B over slice's 512-k range.
// Whole B-slice tile (144x512 bf16 = 144 KB) staged in LDS ONCE (XOR-swizzled,
// byte ^= (row&7)<<4 -> conflict-free ds_read_b128), ONE barrier total, then a
// barrier-free k-loop: A streamed nontemporal with 128-k register double-buffer
// (loads never drained by any barrier). 512 thr = 8 waves x 16 rows.
__global__ __launch_bounds__(512) void k3_partial(const float* __restrict__ Adj,
                                                  const __bf16* __restrict__ Bt,
                                                  float* __restrict__ part) {
  extern __shared__ char btile[];   // BT_BYTES, dynamic (144 KB > 64 KB default)
  const int tid  = threadIdx.x;
  const int lane = tid & 63;
  const int wv   = tid >> 6;
  const int nlo  = lane & 15;
  const int quad = lane >> 4;
  const int rowW = blockIdx.x * 128 + wv * 16;
  const int k0   = blockIdx.y * KRANGE;

  const float* ap = Adj + (size_t)(rowW + nlo) * NN + k0 + quad * 8;

  // chunk-0 A prefetch BEFORE staging: in flight during the LDS fill
  f32x4 aA[8], aB[8];
#pragma unroll
  for (int s4 = 0; s4 < 4; ++s4) {
    aA[2 * s4]     = __builtin_nontemporal_load((const f32x4*)(ap + s4 * 32));
    aA[2 * s4 + 1] = __builtin_nontemporal_load((const f32x4*)(ap + s4 * 32 + 4));
  }

  // stage B tile: per iter each wave copies one full 1024-B row, swizzled write
#pragma unroll
  for (int it = 0; it < 18; ++it) {
    const int row = it * 8 + wv;
    const int swz = (row & 7) << 4;
    u32x4 v = *(const u32x4*)((const char*)(Bt + (size_t)row * NN + k0) + lane * 16);
    *(u32x4*)(btile + row * 1024 + ((lane * 16) ^ swz)) = v;
  }
  __syncthreads();   // the ONLY barrier

  f32x4 acc[9];
#pragma unroll
  for (int nt = 0; nt < 9; ++nt) acc[nt] = f32x4{0.f, 0.f, 0.f, 0.f};

  const int swzr = (nlo & 7) << 4;
  for (int c = 0; c < 4; ++c) {
    if (c < 3) {
      const int kc1 = (c + 1) * 128;
#pragma unroll
      for (int s4 = 0; s4 < 4; ++s4) {
        aB[2 * s4]     = __builtin_nontemporal_load((const f32x4*)(ap + kc1 + s4 * 32));
        aB[2 * s4 + 1] = __builtin_nontemporal_load((const f32x4*)(ap + kc1 + s4 * 32 + 4));
      }
    }
#pragma unroll
    for (int s4 = 0; s4 < 4; ++s4) {
      const int s = c * 4 + s4;
      bf16x8 af = cvt2(aA[2 * s4], aA[2 * s4 + 1]);
      const int cbl = s * 64 + quad * 16;
#pragma unroll
      for (int nt = 0; nt < 9; ++nt) {
        bf16x8 bf = *(const bf16x8*)(btile + (nt * 16 + nlo) * 1024 + (cbl ^ swzr));
        acc[nt] = __builtin_amdgcn_mfma_f32_16x16x32_bf16(af, bf, acc[nt], 0, 0, 0);
      }
    }
    if (c < 3) {
#pragma unroll
      for (int s = 0; s < 8; ++s) aA[s] = aB[s];
    }
  }

  float* pbase = part + ((size_t)blockIdx.y * NN + rowW) * NB;
#pragma unroll
  for (int nt = 0; nt < 8; ++nt)
#pragma unroll
    for (int rg = 0; rg < 4; ++rg)
      pbase[(size_t)(quad * 4 + rg) * NB + nt * 16 + nlo] = acc[nt][rg];
  if (nlo == 0) {
#pragma unroll
    for (int rg = 0; rg < 4; ++rg)
      pbase[(size_t)(quad * 4 + rg) * NB + 128] = acc[8][rg];
  }
}

// K3b: out[row][col] = relu( sum_s part[s][row][col] / sum_s part[s][row][128] )
__global__ __launch_bounds__(256) void k3_reduce(const float* __restrict__ part,
                                                 float* __restrict__ out) {
  const int col = threadIdx.x & 127;
  const int row = blockIdx.x * 2 + (threadIdx.x >> 7);
  float num = 0.f, den = 0.f;
#pragma unroll
  for (int s = 0; s < KSPLIT; ++s) {
    const size_t base = ((size_t)s * NN + row) * NB;
    num += part[base + col];
    den += part[base + 128];
  }
  out[(size_t)row * OUTD + col] = fmaxf(num / den, 0.f);
}

extern "C" void kernel_launch(void* const* d_in, const int* in_sizes, int n_in,
                              void* d_out, int out_size, void* d_ws, size_t ws_size,
                              hipStream_t stream) {
  const float* X  = (const float*)d_in[0];
  const float* A  = (const float*)d_in[1];
  const float* W  = (const float*)d_in[2];
  const float* aw = (const float*)d_in[3];
  float* out = (float*)d_out;

  char* ws = (char*)d_ws;
  __bf16* Bt   = (__bf16*)ws;                   // 144*8192*2    = 2.25 MiB
  float*  part = (float*)(ws + 4194304);        // 16*8192*144*4 = 72 MiB

  static bool attr_done = false;
  if (!attr_done) {
    hipFuncSetAttribute((const void*)k3_partial,
                        hipFuncAttributeMaxDynamicSharedMemorySize, BT_BYTES);
    attr_done = true;
  }

  k1_bt<<<512, 256, 0, stream>>>(X, W, aw, Bt);
  k3_partial<<<dim3(64, KSPLIT), 512, BT_BYTES, stream>>>(A, Bt, part);
  k3_reduce<<<4096, 256, 0, stream>>>(part, out);
}

// Round 5
// 420.264 us; speedup vs baseline: 1.0088x; 1.0088x over previous
//
#include <hip/hip_runtime.h>

typedef float        f32x4  __attribute__((ext_vector_type(4)));
typedef __bf16       bf16x8 __attribute__((ext_vector_type(8)));
typedef unsigned int u32x2  __attribute__((ext_vector_type(2)));

#define NN   8192
#define IND  256
#define OUTD 128
#define NB   144    // part cols: 0..127 = num, 128 = den, 129..143 never read
#define KSPLIT 8
#define KRANGE 1024 // 8192 / KSPLIT
#define KCHUNK 64
#define BSTRIDE 72  // elems: 144-B rows -> bank stride 4, 2-way aliasing only (free)

__device__ __forceinline__ bf16x8 cvt2(f32x4 a, f32x4 b) {
  bf16x8 r;
  r[0]=(__bf16)a[0]; r[1]=(__bf16)a[1]; r[2]=(__bf16)a[2]; r[3]=(__bf16)a[3];
  r[4]=(__bf16)b[0]; r[5]=(__bf16)b[1]; r[6]=(__bf16)b[2]; r[7]=(__bf16)b[3];
  return r;
}

// K1 (fused): Wh = X@W^T via MFMA (4-way K-split across waves, LDS merge),
// e = relu(Wh).a_w (16-lane butterfly allreduce), then write B^T directly:
// Bt[n][j] = exp(e_j)*Wh[j][n] (n<128), Bt[128][j] = exp(e_j), rows 129..143 = 0.
__global__ __launch_bounds__(256) void k1_bt(const float* __restrict__ X,
                                             const float* __restrict__ W,
                                             const float* __restrict__ aw,
                                             __bf16* __restrict__ Bt) {
  __shared__ float red[4][16][128];   // 32 KB
  const int tid  = threadIdx.x;
  const int lane = tid & 63;
  const int wave = tid >> 6;
  const int nlo  = lane & 15;
  const int quad = lane >> 4;
  const int rowBase = blockIdx.x * 16;

  const float* xp = X + (size_t)(rowBase + nlo) * IND + wave * 64 + quad * 8;
  f32x4 acc[8];
#pragma unroll
  for (int nt = 0; nt < 8; ++nt) acc[nt] = f32x4{0.f, 0.f, 0.f, 0.f};

#pragma unroll
  for (int kb = 0; kb < 64; kb += 32) {
    f32x4 a0 = *(const f32x4*)(xp + kb);
    f32x4 a1 = *(const f32x4*)(xp + kb + 4);
    bf16x8 af = cvt2(a0, a1);
#pragma unroll
    for (int nt = 0; nt < 8; ++nt) {
      const float* wp = W + (size_t)(nt * 16 + nlo) * IND + wave * 64 + kb + quad * 8;
      f32x4 b0 = *(const f32x4*)wp;
      f32x4 b1 = *(const f32x4*)(wp + 4);
      acc[nt] = __builtin_amdgcn_mfma_f32_16x16x32_bf16(af, cvt2(b0, b1), acc[nt], 0, 0, 0);
    }
  }
#pragma unroll
  for (int nt = 0; nt < 8; ++nt)
#pragma unroll
    for (int rg = 0; rg < 4; ++rg)
      red[wave][quad * 4 + rg][nt * 16 + nlo] = acc[nt][rg];
  __syncthreads();

  const int r  = tid >> 4;
  const int c0 = (tid & 15) * 8;
  f32x4 vlo = *(const f32x4*)&red[0][r][c0];
  f32x4 vhi = *(const f32x4*)&red[0][r][c0 + 4];
#pragma unroll
  for (int w = 1; w < 4; ++w) {
    vlo += *(const f32x4*)&red[w][r][c0];
    vhi += *(const f32x4*)&red[w][r][c0 + 4];
  }
  float pa = 0.f;
#pragma unroll
  for (int i = 0; i < 4; ++i) {
    pa += fmaxf(vlo[i], 0.f) * aw[c0 + i];
    pa += fmaxf(vhi[i], 0.f) * aw[c0 + 4 + i];
  }
#pragma unroll
  for (int off = 8; off; off >>= 1) pa += __shfl_xor(pa, off, 64);  // 16-lane allreduce
  const float wexp = expf(pa);
  const int j = rowBase + r;

#pragma unroll
  for (int i = 0; i < 4; ++i)
    Bt[(size_t)(c0 + i) * NN + j] = (__bf16)(vlo[i] * wexp);
#pragma unroll
  for (int i = 0; i < 4; ++i)
    Bt[(size_t)(c0 + 4 + i) * NN + j] = (__bf16)(vhi[i] * wexp);
  if ((tid & 15) == 0)
    Bt[(size_t)OUTD * NN + j] = (__bf16)wexp;           // denominator row
  if (tid < 120) {                                       // zero rows 129..143
    const int row = 129 + (tid >> 3);
    const int cc  = rowBase + (tid & 7) * 2;
    Bt[(size_t)row * NN + cc]     = (__bf16)0.f;
    Bt[(size_t)row * NN + cc + 1] = (__bf16)0.f;
  }
}

// K3a: part[slice][8192 x NB] = Adj(->bf16) @ B over slice's 1024-k range.
// R0 loop shape (proven ~113 us at 16 waves/CU) with KCHUNK=64 -> LDS 20.25 KB,
// VGPR ~80 -> ~6 blocks/CU = 24 waves/CU. Occupancy is the lever (R0..R4 data:
// k3a time tracks inversely with resident waves; ILP tricks that cost waves lose).
__global__ __launch_bounds__(256, 4) void k3_partial(const float* __restrict__ Adj,
                                                     const __bf16* __restrict__ Bt,
                                                     float* __restrict__ part) {
  __shared__ unsigned short bt[NB * BSTRIDE];  // 20.25 KB
  const int tid  = threadIdx.x;
  const int lane = tid & 63;
  const int wave = tid >> 6;
  const int nlo  = lane & 15;
  const int quad = lane >> 4;
  const int rowW = blockIdx.x * 64 + wave * 16;
  const int k0   = blockIdx.y * KRANGE;

  const int brow = tid >> 4;        // 0..15 (+ rr*16)
  const int bcol = (tid & 15) * 4;  // bf16 elems, 8 B per thread

  f32x4 acc[9];
#pragma unroll
  for (int nt = 0; nt < 9; ++nt) acc[nt] = f32x4{0.f, 0.f, 0.f, 0.f};

  const float*  ap = Adj + (size_t)(rowW + nlo) * NN + quad * 8 + k0;
  const __bf16* bq = Bt + (size_t)brow * NN + k0 + bcol;

  for (int c = 0; c < KRANGE / KCHUNK; ++c) {
    const int kc = c * KCHUNK;
    // B loads first, then A prefetch for the chunk: all in flight together,
    // drained once at the pre-MFMA barrier, hidden by ~24 resident waves/CU.
    u32x2 breg[9];
#pragma unroll
    for (int rr = 0; rr < 9; ++rr)
      breg[rr] = *(const u32x2*)(bq + (size_t)(rr * 16) * NN + kc);
    f32x4 areg[4];
#pragma unroll
    for (int s = 0; s < 2; ++s) {
      areg[2 * s]     = __builtin_nontemporal_load((const f32x4*)(ap + kc + s * 32));
      areg[2 * s + 1] = __builtin_nontemporal_load((const f32x4*)(ap + kc + s * 32 + 4));
    }
#pragma unroll
    for (int rr = 0; rr < 9; ++rr)
      *(u32x2*)(bt + (rr * 16 + brow) * BSTRIDE + bcol) = breg[rr];
    __syncthreads();
#pragma unroll
    for (int s = 0; s < 2; ++s) {
      bf16x8 af = cvt2(areg[2 * s], areg[2 * s + 1]);
      const unsigned short* bp = bt + s * 32 + quad * 8;
#pragma unroll
      for (int nt = 0; nt < 9; ++nt) {
        bf16x8 bf = *(const bf16x8*)(bp + (nt * 16 + nlo) * BSTRIDE);
        acc[nt] = __builtin_amdgcn_mfma_f32_16x16x32_bf16(af, bf, acc[nt], 0, 0, 0);
      }
    }
    __syncthreads();
  }

  float* pbase = part + ((size_t)blockIdx.y * NN + rowW) * NB;
#pragma unroll
  for (int nt = 0; nt < 8; ++nt)
#pragma unroll
    for (int rg = 0; rg < 4; ++rg)
      pbase[(size_t)(quad * 4 + rg) * NB + nt * 16 + nlo] = acc[nt][rg];
  if (nlo == 0) {
#pragma unroll
    for (int rg = 0; rg < 4; ++rg)
      pbase[(size_t)(quad * 4 + rg) * NB + 128] = acc[8][rg];
  }
}

// K3b: out[row][col] = relu( sum_s part[s][row][col] / sum_s part[s][row][128] )
__global__ __launch_bounds__(256) void k3_reduce(const float* __restrict__ part,
                                                 float* __restrict__ out) {
  const int col = threadIdx.x & 127;
  const int row = blockIdx.x * 2 + (threadIdx.x >> 7);
  float num = 0.f, den = 0.f;
#pragma unroll
  for (int s = 0; s < KSPLIT; ++s) {
    const size_t base = ((size_t)s * NN + row) * NB;
    num += part[base + col];
    den += part[base + 128];
  }
  out[(size_t)row * OUTD + col] = fmaxf(num / den, 0.f);
}

extern "C" void kernel_launch(void* const* d_in, const int* in_sizes, int n_in,
                              void* d_out, int out_size, void* d_ws, size_t ws_size,
                              hipStream_t stream) {
  const float* X  = (const float*)d_in[0];
  const float* A  = (const float*)d_in[1];
  const float* W  = (const float*)d_in[2];
  const float* aw = (const float*)d_in[3];
  float* out = (float*)d_out;

  char* ws = (char*)d_ws;
  __bf16* Bt   = (__bf16*)ws;                   // 144*8192*2   = 2.25 MiB
  float*  part = (float*)(ws + 4194304);        // 8*8192*144*4 = 37.75 MiB

  k1_bt<<<512, 256, 0, stream>>>(X, W, aw, Bt);
  k3_partial<<<dim3(128, KSPLIT), 256, 0, stream>>>(A, Bt, part);
  k3_reduce<<<4096, 256, 0, stream>>>(part, out);
}

// Round 6
// 403.444 us; speedup vs baseline: 1.0508x; 1.0417x over previous
//
#include <hip/hip_runtime.h>

typedef float        f32x4  __attribute__((ext_vector_type(4)));
typedef __bf16       bf16x8 __attribute__((ext_vector_type(8)));
typedef unsigned int u32x4  __attribute__((ext_vector_type(4)));

#define NN   8192
#define IND  256
#define OUTD 128
#define NB   144    // part cols: 0..127 = num, 128 = den, 129..143 never read
#define KSPLIT 8
#define KRANGE 1024 // 8192 / KSPLIT
#define KCHUNK 128
#define BSTRIDE 136 // 128 + 8 bf16 pad: 272 B rows -> 2-way LDS aliasing only (free)

__device__ __forceinline__ bf16x8 cvt2(f32x4 a, f32x4 b) {
  bf16x8 r;
  r[0]=(__bf16)a[0]; r[1]=(__bf16)a[1]; r[2]=(__bf16)a[2]; r[3]=(__bf16)a[3];
  r[4]=(__bf16)b[0]; r[5]=(__bf16)b[1]; r[6]=(__bf16)b[2]; r[7]=(__bf16)b[3];
  return r;
}

// K1 (fused): Wh = X@W^T via MFMA (4-way K-split across waves, LDS merge),
// e = relu(Wh).a_w (16-lane butterfly allreduce), then write B^T directly:
// Bt[n][j] = exp(e_j)*Wh[j][n] (n<128), Bt[128][j] = exp(e_j), rows 129..143 = 0.
// High-occupancy: 512 blocks x 256 thr (vs 0.5 waves/SIMD of the old 128-thr k1).
__global__ __launch_bounds__(256) void k1_bt(const float* __restrict__ X,
                                             const float* __restrict__ W,
                                             const float* __restrict__ aw,
                                             __bf16* __restrict__ Bt) {
  __shared__ float red[4][16][128];   // 32 KB
  const int tid  = threadIdx.x;
  const int lane = tid & 63;
  const int wave = tid >> 6;
  const int nlo  = lane & 15;
  const int quad = lane >> 4;
  const int rowBase = blockIdx.x * 16;

  const float* xp = X + (size_t)(rowBase + nlo) * IND + wave * 64 + quad * 8;
  f32x4 acc[8];
#pragma unroll
  for (int nt = 0; nt < 8; ++nt) acc[nt] = f32x4{0.f, 0.f, 0.f, 0.f};

#pragma unroll
  for (int kb = 0; kb < 64; kb += 32) {
    f32x4 a0 = *(const f32x4*)(xp + kb);
    f32x4 a1 = *(const f32x4*)(xp + kb + 4);
    bf16x8 af = cvt2(a0, a1);
#pragma unroll
    for (int nt = 0; nt < 8; ++nt) {
      const float* wp = W + (size_t)(nt * 16 + nlo) * IND + wave * 64 + kb + quad * 8;
      f32x4 b0 = *(const f32x4*)wp;
      f32x4 b1 = *(const f32x4*)(wp + 4);
      acc[nt] = __builtin_amdgcn_mfma_f32_16x16x32_bf16(af, cvt2(b0, b1), acc[nt], 0, 0, 0);
    }
  }
#pragma unroll
  for (int nt = 0; nt < 8; ++nt)
#pragma unroll
    for (int rg = 0; rg < 4; ++rg)
      red[wave][quad * 4 + rg][nt * 16 + nlo] = acc[nt][rg];
  __syncthreads();

  const int r  = tid >> 4;
  const int c0 = (tid & 15) * 8;
  f32x4 vlo = *(const f32x4*)&red[0][r][c0];
  f32x4 vhi = *(const f32x4*)&red[0][r][c0 + 4];
#pragma unroll
  for (int w = 1; w < 4; ++w) {
    vlo += *(const f32x4*)&red[w][r][c0];
    vhi += *(const f32x4*)&red[w][r][c0 + 4];
  }
  float pa = 0.f;
#pragma unroll
  for (int i = 0; i < 4; ++i) {
    pa += fmaxf(vlo[i], 0.f) * aw[c0 + i];
    pa += fmaxf(vhi[i], 0.f) * aw[c0 + 4 + i];
  }
#pragma unroll
  for (int off = 8; off; off >>= 1) pa += __shfl_xor(pa, off, 64);  // 16-lane allreduce
  const float wexp = expf(pa);
  const int j = rowBase + r;

#pragma unroll
  for (int i = 0; i < 4; ++i)
    Bt[(size_t)(c0 + i) * NN + j] = (__bf16)(vlo[i] * wexp);
#pragma unroll
  for (int i = 0; i < 4; ++i)
    Bt[(size_t)(c0 + 4 + i) * NN + j] = (__bf16)(vhi[i] * wexp);
  if ((tid & 15) == 0)
    Bt[(size_t)OUTD * NN + j] = (__bf16)wexp;           // denominator row
  if (tid < 120) {                                       // zero rows 129..143
    const int row = 129 + (tid >> 3);
    const int cc  = rowBase + (tid & 7) * 2;
    Bt[(size_t)row * NN + cc]     = (__bf16)0.f;
    Bt[(size_t)row * NN + cc + 1] = (__bf16)0.f;
  }
}

// K3a: part[slice][8192 x NB] = Adj(->bf16) @ B over slice's 1024-k range.
// EXACT R0 structure (best measured k3a, ~114 us): KCHUNK=128, 16B B-staging,
// B-loads-then-A-prefetch-then-ds_write-sync, 18 MFMAs per barrier pair,
// 4 blocks/CU (LDS 38.25 KB, launch_bounds(256,4)). Only change vs R0:
// epilogue skips junk cols 129..143.
__global__ __launch_bounds__(256, 4) void k3_partial(const float* __restrict__ Adj,
                                                     const __bf16* __restrict__ Bt,
                                                     float* __restrict__ part) {
  __shared__ unsigned short bt[NB * BSTRIDE];  // 38.25 KB
  const int tid  = threadIdx.x;
  const int lane = tid & 63;
  const int wave = tid >> 6;
  const int nlo  = lane & 15;
  const int quad = lane >> 4;
  const int rowW = blockIdx.x * 64 + wave * 16;
  const int k0   = blockIdx.y * KRANGE;

  const int brow = tid >> 4;        // 0..15, + rr*16 below
  const int bcol = (tid & 15) * 8;  // bf16 elems, 16B per thread

  f32x4 acc[9];
#pragma unroll
  for (int nt = 0; nt < 9; ++nt) acc[nt] = f32x4{0.f, 0.f, 0.f, 0.f};

  const float* ap = Adj + (size_t)(rowW + nlo) * NN + quad * 8 + k0;

  for (int c = 0; c < KRANGE / KCHUNK; ++c) {
    const int kc = k0 + c * KCHUNK;
    // B stage: issue global B loads FIRST so the ds_write wait leaves A in flight
    u32x4 breg[9];
#pragma unroll
    for (int rr = 0; rr < 9; ++rr)
      breg[rr] = *(const u32x4*)(Bt + (size_t)(rr * 16 + brow) * NN + kc + bcol);
    // A prefetch for the whole chunk (nontemporal: streamed once)
    f32x4 areg[8];
#pragma unroll
    for (int s = 0; s < 4; ++s) {
      areg[2 * s]     = __builtin_nontemporal_load((const f32x4*)(ap + c * KCHUNK + s * 32));
      areg[2 * s + 1] = __builtin_nontemporal_load((const f32x4*)(ap + c * KCHUNK + s * 32 + 4));
    }
#pragma unroll
    for (int rr = 0; rr < 9; ++rr)
      *(u32x4*)(bt + (rr * 16 + brow) * BSTRIDE + bcol) = breg[rr];
    __syncthreads();
#pragma unroll
    for (int s = 0; s < 4; ++s) {
      bf16x8 af = cvt2(areg[2 * s], areg[2 * s + 1]);
      const unsigned short* bp = bt + s * 32 + quad * 8;
#pragma unroll
      for (int nt = 0; nt < 9; ++nt) {
        bf16x8 bf = *(const bf16x8*)(bp + (nt * 16 + nlo) * BSTRIDE);
        acc[nt] = __builtin_amdgcn_mfma_f32_16x16x32_bf16(af, bf, acc[nt], 0, 0, 0);
      }
    }
    __syncthreads();
  }

  float* pbase = part + ((size_t)blockIdx.y * NN + rowW) * NB;
#pragma unroll
  for (int nt = 0; nt < 8; ++nt)
#pragma unroll
    for (int rg = 0; rg < 4; ++rg)
      pbase[(size_t)(quad * 4 + rg) * NB + nt * 16 + nlo] = acc[nt][rg];
  if (nlo == 0) {
#pragma unroll
    for (int rg = 0; rg < 4; ++rg)
      pbase[(size_t)(quad * 4 + rg) * NB + 128] = acc[8][rg];
  }
}

// K3b: out[row][col] = relu( sum_s part[s][row][col] / sum_s part[s][row][128] )
__global__ __launch_bounds__(256) void k3_reduce(const float* __restrict__ part,
                                                 float* __restrict__ out) {
  const int col = threadIdx.x & 127;
  const int row = blockIdx.x * 2 + (threadIdx.x >> 7);
  float num = 0.f, den = 0.f;
#pragma unroll
  for (int s = 0; s < KSPLIT; ++s) {
    const size_t base = ((size_t)s * NN + row) * NB;
    num += part[base + col];
    den += part[base + 128];
  }
  out[(size_t)row * OUTD + col] = fmaxf(num / den, 0.f);
}

extern "C" void kernel_launch(void* const* d_in, const int* in_sizes, int n_in,
                              void* d_out, int out_size, void* d_ws, size_t ws_size,
                              hipStream_t stream) {
  const float* X  = (const float*)d_in[0];
  const float* A  = (const float*)d_in[1];
  const float* W  = (const float*)d_in[2];
  const float* aw = (const float*)d_in[3];
  float* out = (float*)d_out;

  char* ws = (char*)d_ws;
  __bf16* Bt   = (__bf16*)ws;                   // 144*8192*2   = 2.25 MiB
  float*  part = (float*)(ws + 4194304);        // 8*8192*144*4 = 37.75 MiB

  k1_bt<<<512, 256, 0, stream>>>(X, W, aw, Bt);
  k3_partial<<<dim3(128, KSPLIT), 256, 0, stream>>>(A, Bt, part);
  k3_reduce<<<4096, 256, 0, stream>>>(part, out);
}

// Round 7
// 400.064 us; speedup vs baseline: 1.0597x; 1.0085x over previous
//
#include <hip/hip_runtime.h>

typedef float        f32x4  __attribute__((ext_vector_type(4)));
typedef __bf16       bf16x8 __attribute__((ext_vector_type(8)));
typedef unsigned int u32x4  __attribute__((ext_vector_type(4)));

#define NN   8192
#define IND  256
#define OUTD 128
#define NB   144    // part cols: 0..127 = num, 128 = den, 129..143 never read
#define KSPLIT 8
#define KRANGE 1024 // 8192 / KSPLIT
#define KCHUNK 128
#define ASTR 136    // LDS row stride (bf16 elems): 272-B rows -> <=2-way alias (free)
#define BSTR 136

__device__ __forceinline__ bf16x8 cvt2(f32x4 a, f32x4 b) {
  bf16x8 r;
  r[0]=(__bf16)a[0]; r[1]=(__bf16)a[1]; r[2]=(__bf16)a[2]; r[3]=(__bf16)a[3];
  r[4]=(__bf16)b[0]; r[5]=(__bf16)b[1]; r[6]=(__bf16)b[2]; r[7]=(__bf16)b[3];
  return r;
}

// K1 (fused): Wh = X@W^T via MFMA (4-way K-split across waves, LDS merge),
// e = relu(Wh).a_w (16-lane butterfly allreduce), then write B^T directly:
// Bt[n][j] = exp(e_j)*Wh[j][n] (n<128), Bt[128][j] = exp(e_j), rows 129..143 = 0.
__global__ __launch_bounds__(256) void k1_bt(const float* __restrict__ X,
                                             const float* __restrict__ W,
                                             const float* __restrict__ aw,
                                             __bf16* __restrict__ Bt) {
  __shared__ float red[4][16][128];   // 32 KB
  const int tid  = threadIdx.x;
  const int lane = tid & 63;
  const int wave = tid >> 6;
  const int nlo  = lane & 15;
  const int quad = lane >> 4;
  const int rowBase = blockIdx.x * 16;

  const float* xp = X + (size_t)(rowBase + nlo) * IND + wave * 64 + quad * 8;
  f32x4 acc[8];
#pragma unroll
  for (int nt = 0; nt < 8; ++nt) acc[nt] = f32x4{0.f, 0.f, 0.f, 0.f};

#pragma unroll
  for (int kb = 0; kb < 64; kb += 32) {
    f32x4 a0 = *(const f32x4*)(xp + kb);
    f32x4 a1 = *(const f32x4*)(xp + kb + 4);
    bf16x8 af = cvt2(a0, a1);
#pragma unroll
    for (int nt = 0; nt < 8; ++nt) {
      const float* wp = W + (size_t)(nt * 16 + nlo) * IND + wave * 64 + kb + quad * 8;
      f32x4 b0 = *(const f32x4*)wp;
      f32x4 b1 = *(const f32x4*)(wp + 4);
      acc[nt] = __builtin_amdgcn_mfma_f32_16x16x32_bf16(af, cvt2(b0, b1), acc[nt], 0, 0, 0);
    }
  }
#pragma unroll
  for (int nt = 0; nt < 8; ++nt)
#pragma unroll
    for (int rg = 0; rg < 4; ++rg)
      red[wave][quad * 4 + rg][nt * 16 + nlo] = acc[nt][rg];
  __syncthreads();

  const int r  = tid >> 4;
  const int c0 = (tid & 15) * 8;
  f32x4 vlo = *(const f32x4*)&red[0][r][c0];
  f32x4 vhi = *(const f32x4*)&red[0][r][c0 + 4];
#pragma unroll
  for (int w = 1; w < 4; ++w) {
    vlo += *(const f32x4*)&red[w][r][c0];
    vhi += *(const f32x4*)&red[w][r][c0 + 4];
  }
  float pa = 0.f;
#pragma unroll
  for (int i = 0; i < 4; ++i) {
    pa += fmaxf(vlo[i], 0.f) * aw[c0 + i];
    pa += fmaxf(vhi[i], 0.f) * aw[c0 + 4 + i];
  }
#pragma unroll
  for (int off = 8; off; off >>= 1) pa += __shfl_xor(pa, off, 64);  // 16-lane allreduce
  const float wexp = expf(pa);
  const int j = rowBase + r;

#pragma unroll
  for (int i = 0; i < 4; ++i)
    Bt[(size_t)(c0 + i) * NN + j] = (__bf16)(vlo[i] * wexp);
#pragma unroll
  for (int i = 0; i < 4; ++i)
    Bt[(size_t)(c0 + 4 + i) * NN + j] = (__bf16)(vhi[i] * wexp);
  if ((tid & 15) == 0)
    Bt[(size_t)OUTD * NN + j] = (__bf16)wexp;           // denominator row
  if (tid < 120) {                                       // zero rows 129..143
    const int row = 129 + (tid >> 3);
    const int cc  = rowBase + (tid & 7) * 2;
    Bt[(size_t)row * NN + cc]     = (__bf16)0.f;
    Bt[(size_t)row * NN + cc + 1] = (__bf16)0.f;
  }
}

// K3a: part[slice][8192 x NB] = Adj(->bf16) @ B over slice's 1024-k range.
// NEW vs R6: A is loaded COALESCED (16 lanes = 512 contiguous bytes of one row)
// and staged through LDS, instead of register-direct 16-row/32KB-stride fragment
// gathers. The gather pattern is the one invariant shared by every ~200us k3a
// variant (R0..R6); fills prove coalesced traffic runs at 6.7 TB/s.
// 512 thr = 8 waves, 128 M-rows/block; LDS 72.25 KB -> 2 blocks/CU = 16 waves/CU.
__global__ __launch_bounds__(512, 4) void k3_partial(const float* __restrict__ Adj,
                                                     const __bf16* __restrict__ Bt,
                                                     float* __restrict__ part) {
  __shared__ unsigned short aT[128 * ASTR];  // 34 KB
  __shared__ unsigned short bT[NB * BSTR];   // 38.25 KB
  const int tid  = threadIdx.x;
  const int lane = tid & 63;
  const int wv   = tid >> 6;
  const int nlo  = lane & 15;
  const int quad = lane >> 4;
  const int rowW = blockIdx.x * 128 + wv * 16;
  const int k0   = blockIdx.y * KRANGE;

  // coalesced staging map: 16 threads cover one row's 128-col chunk
  const int lrow = tid >> 4;          // 0..31, + r*32 per round
  const int lcol = (tid & 15) * 8;    // elems (floats for A, bf16 for B)

  const float*  aload = Adj + (size_t)((size_t)blockIdx.x * 128 + lrow) * NN + k0 + lcol;
  const __bf16* bload = Bt + (size_t)lrow * NN + k0 + lcol;

  f32x4 acc[9];
#pragma unroll
  for (int nt = 0; nt < 9; ++nt) acc[nt] = f32x4{0.f, 0.f, 0.f, 0.f};

  for (int c = 0; c < KRANGE / KCHUNK; ++c) {
    const int kc = c * KCHUNK;
    // issue ALL global loads first (B then A), single drain at the barrier
    u32x4 breg[5];
#pragma unroll
    for (int r = 0; r < 4; ++r)
      breg[r] = *(const u32x4*)(bload + (size_t)(r * 32) * NN + kc);
    if (lrow < 16)  // rows 128..143 (denominator + zeros)
      breg[4] = *(const u32x4*)(bload + (size_t)128 * NN + kc);
    f32x4 areg[8];
#pragma unroll
    for (int r = 0; r < 4; ++r) {
      areg[2 * r]     = __builtin_nontemporal_load((const f32x4*)(aload + (size_t)(r * 32) * NN + kc));
      areg[2 * r + 1] = __builtin_nontemporal_load((const f32x4*)(aload + (size_t)(r * 32) * NN + kc + 4));
    }
    // LDS writes
#pragma unroll
    for (int r = 0; r < 4; ++r)
      *(u32x4*)(bT + (r * 32 + lrow) * BSTR + lcol) = breg[r];
    if (lrow < 16)
      *(u32x4*)(bT + (128 + lrow) * BSTR + lcol) = breg[4];
#pragma unroll
    for (int r = 0; r < 4; ++r)
      *(bf16x8*)(aT + (r * 32 + lrow) * ASTR + lcol) = cvt2(areg[2 * r], areg[2 * r + 1]);
    __syncthreads();

    // MFMA: fragments from LDS (A already bf16)
#pragma unroll
    for (int s = 0; s < 4; ++s) {
      bf16x8 af = *(const bf16x8*)(aT + (wv * 16 + nlo) * ASTR + s * 32 + quad * 8);
#pragma unroll
      for (int nt = 0; nt < 9; ++nt) {
        bf16x8 bf = *(const bf16x8*)(bT + (nt * 16 + nlo) * BSTR + s * 32 + quad * 8);
        acc[nt] = __builtin_amdgcn_mfma_f32_16x16x32_bf16(af, bf, acc[nt], 0, 0, 0);
      }
    }
    __syncthreads();
  }

  float* pbase = part + ((size_t)blockIdx.y * NN + rowW) * NB;
#pragma unroll
  for (int nt = 0; nt < 8; ++nt)
#pragma unroll
    for (int rg = 0; rg < 4; ++rg)
      pbase[(size_t)(quad * 4 + rg) * NB + nt * 16 + nlo] = acc[nt][rg];
  if (nlo == 0) {
#pragma unroll
    for (int rg = 0; rg < 4; ++rg)
      pbase[(size_t)(quad * 4 + rg) * NB + 128] = acc[8][rg];
  }
}

// K3b: out[row][col] = relu( sum_s part[s][row][col] / sum_s part[s][row][128] )
__global__ __launch_bounds__(256) void k3_reduce(const float* __restrict__ part,
                                                 float* __restrict__ out) {
  const int col = threadIdx.x & 127;
  const int row = blockIdx.x * 2 + (threadIdx.x >> 7);
  float num = 0.f, den = 0.f;
#pragma unroll
  for (int s = 0; s < KSPLIT; ++s) {
    const size_t base = ((size_t)s * NN + row) * NB;
    num += part[base + col];
    den += part[base + 128];
  }
  out[(size_t)row * OUTD + col] = fmaxf(num / den, 0.f);
}

extern "C" void kernel_launch(void* const* d_in, const int* in_sizes, int n_in,
                              void* d_out, int out_size, void* d_ws, size_t ws_size,
                              hipStream_t stream) {
  const float* X  = (const float*)d_in[0];
  const float* A  = (const float*)d_in[1];
  const float* W  = (const float*)d_in[2];
  const float* aw = (const float*)d_in[3];
  float* out = (float*)d_out;

  char* ws = (char*)d_ws;
  __bf16* Bt   = (__bf16*)ws;                   // 144*8192*2   = 2.25 MiB
  float*  part = (float*)(ws + 4194304);        // 8*8192*144*4 = 37.75 MiB

  k1_bt<<<512, 256, 0, stream>>>(X, W, aw, Bt);
  k3_partial<<<dim3(64, KSPLIT), 512, 0, stream>>>(A, Bt, part);
  k3_reduce<<<4096, 256, 0, stream>>>(part, out);
}